// Round 2
// baseline (3057.515 us; speedup 1.0000x reference)
//
#include <hip/hip_runtime.h>
#include <math.h>

#define GRID_N 512
#define IM_N   256
#define NCOIL  8
#define NK     131072
#define PLANE  (GRID_N*GRID_N)
#define JW     6
#define BETA_F 13.8551003f   /* pi*sqrt((6/2)^2*(2-0.5)^2 - 0.8) */

struct cplx { float x, y; };

__device__ __forceinline__ float bessel_i0f(float x){
  // Abramowitz & Stegun 9.8.1 / 9.8.2, rel err < 2e-7
  if (x < 3.75f){
    float t = x*(1.0f/3.75f); t = t*t;
    return 1.0f + t*(3.5156229f + t*(3.0899424f + t*(1.2067492f
           + t*(0.2659732f + t*(0.0360768f + t*0.0045813f)))));
  } else {
    float t = 3.75f/x;
    float p = 0.39894228f + t*(0.01328592f + t*(0.00225319f + t*(-0.00157565f
            + t*(0.00916281f + t*(-0.02057706f + t*(0.02635537f
            + t*(-0.01647633f + t*0.00392377f)))))));
    return p * __expf(x) * rsqrtf(x);
  }
}

// Kaiser-Bessel apodization correction row table sc[256]
__global__ void k_sc_table(float* sc){
  int i = threadIdx.x;
  if (i >= IM_N) return;
  float n  = (i - IM_N*0.5f) * (1.0f/GRID_N);
  float pj = 3.14159265358979f * (float)JW * n;
  float t  = BETA_F*BETA_F - pj*pj;
  float sp = sqrtf(fmaxf(t, 1e-12f));
  float sn = sqrtf(fmaxf(-t, 1e-12f));
  float ft = (t > 0.0f) ? (sinhf(sp)/sp) : (sinf(sn)/sn);
  float sc0 = sinhf(BETA_F)/BETA_F;
  sc[i] = sc0/ft;
}

__global__ void k_zero4(float4* p, int n4){
  int i = blockIdx.x*blockDim.x + threadIdx.x;
  if (i < n4) p[i] = make_float4(0.f,0.f,0.f,0.f);
}

__global__ void k_zero1(float* p, int n){
  int i = blockIdx.x*blockDim.x + threadIdx.x;
  if (i < n) p[i] = 0.f;
}

// coil_images * sc2 into padded 512^2 grids (A zeroed beforehand)
template<int G>
__global__ void k_fill(const float* __restrict__ ximg, const float* __restrict__ sr,
                       const float* __restrict__ si, const float* __restrict__ sc,
                       cplx* __restrict__ A, int c0){
  int idx = blockIdx.x*blockDim.x + threadIdx.x;   // c*65536 + y*256 + x (local coil)
  if (idx >= G*IM_N*IM_N) return;
  int c   = idx >> 16;
  int pix = idx & 65535;
  int y = pix >> 8;
  int x = pix & 255;
  float v = ximg[pix] * sc[y]*sc[x];
  int gidx = ((c0 + c) << 16) | pix;
  cplx o; o.x = v * sr[gidx]; o.y = v * si[gidx];
  A[(size_t)c*PLANE + y*GRID_N + x] = o;
}

// in-place 512-pt radix-2 FFT on each contiguous row; DIR=-1 fwd, +1 inv(unnorm)
template<int DIR>
__global__ void k_fft_rows(cplx* __restrict__ buf, float scale){
  __shared__ cplx lds[GRID_N];
  cplx* p = buf + (size_t)blockIdx.x * GRID_N;
  int tid = threadIdx.x;                       // 256 threads
  for (int i = tid; i < GRID_N; i += 256){
    int r = __brev((unsigned)i) >> 23;         // 9-bit reverse
    lds[r] = p[i];
  }
  __syncthreads();
  for (int half = 1; half < GRID_N; half <<= 1){
    int j = tid & (half-1);
    int k = ((tid & ~(half-1)) << 1) | j;
    float ang = (float)DIR * 3.14159265358979f * (float)j / (float)half;
    float sw, cw; __sincosf(ang, &sw, &cw);
    cplx u = lds[k];
    cplx v = lds[k+half];
    cplx t; t.x = v.x*cw - v.y*sw; t.y = v.x*sw + v.y*cw;
    lds[k].x      = u.x + t.x; lds[k].y      = u.y + t.y;
    lds[k+half].x = u.x - t.x; lds[k+half].y = u.y - t.y;
    __syncthreads();
  }
  for (int i = tid; i < GRID_N; i += 256){
    cplx v = lds[i]; v.x *= scale; v.y *= scale; p[i] = v;
  }
}

// 512x512 tile transpose per coil plane, out[X][Y] = in[Y][X]
__global__ void k_transpose(const cplx* __restrict__ in, cplx* __restrict__ out){
  __shared__ cplx tile[32][33];
  int c  = blockIdx.z;
  int x0 = blockIdx.x*32, y0 = blockIdx.y*32;
  const cplx* ip = in  + (size_t)c*PLANE;
  cplx*       op = out + (size_t)c*PLANE;
  int tx = threadIdx.x, ty = threadIdx.y;      // (32,8)
  for (int dy = 0; dy < 32; dy += 8)
    tile[ty+dy][tx] = ip[(size_t)(y0+ty+dy)*GRID_N + (x0+tx)];
  __syncthreads();
  for (int dy = 0; dy < 32; dy += 8)
    op[(size_t)(x0+ty+dy)*GRID_N + (y0+tx)] = tile[tx][ty+dy];
}

// per-sample: 6x6 gather from KT (kg transposed), lambda blend, 6x6 scatter to HT
template<int G>
__global__ void k_gather_scatter(const float* __restrict__ ktraj,
                                 const float* __restrict__ yre,
                                 const float* __restrict__ yim,
                                 const float* __restrict__ lraw,
                                 const cplx* __restrict__ KT,
                                 float* __restrict__ HT, int c0){
  int k = blockIdx.x*blockDim.x + threadIdx.x;
  if (k >= NK) return;
  float lam   = 1.0f/(1.0f + __expf(-lraw[0]));
  float omlam = 1.0f - lam;
  const float kscale = (float)GRID_N / (2.0f*3.14159265358979f);

  int iy[JW], ix[JW]; float wy[JW], wx[JW];
  {
    float tm = ktraj[k] * kscale;
    float base = floorf(tm - 3.0f);
    #pragma unroll
    for (int j = 0; j < JW; ++j){
      float fidx = base + (float)(j+1);
      float u = tm - fidx;
      float uu = u*(1.0f/3.0f);
      float q = fmaxf(1.0f - uu*uu, 0.0f);
      wy[j] = bessel_i0f(BETA_F*sqrtf(q)) * (1.0f/6.0f);
      iy[j] = ((int)fidx) & (GRID_N-1);
    }
  }
  {
    float tm = ktraj[NK + k] * kscale;
    float base = floorf(tm - 3.0f);
    #pragma unroll
    for (int j = 0; j < JW; ++j){
      float fidx = base + (float)(j+1);
      float u = tm - fidx;
      float uu = u*(1.0f/3.0f);
      float q = fmaxf(1.0f - uu*uu, 0.0f);
      wx[j] = bessel_i0f(BETA_F*sqrtf(q)) * (1.0f/6.0f);
      ix[j] = ((int)fidx) & (GRID_N-1);
    }
  }

  float accx[G], accy[G];
  #pragma unroll
  for (int c = 0; c < G; ++c){ accx[c] = 0.f; accy[c] = 0.f; }

  #pragma unroll
  for (int jx = 0; jx < JW; ++jx){
    int ox = ix[jx]*GRID_N;
    #pragma unroll
    for (int jy = 0; jy < JW; ++jy){
      float w2 = wx[jx]*wy[jy];
      size_t o = (size_t)(ox + iy[jy]);
      #pragma unroll
      for (int c = 0; c < G; ++c){
        cplx v = KT[(size_t)c*PLANE + o];
        accx[c] += w2*v.x; accy[c] += w2*v.y;
      }
    }
  }

  float kdcx[G], kdcy[G];
  #pragma unroll
  for (int c = 0; c < G; ++c){
    kdcx[c] = lam*accx[c] + omlam*yre[(size_t)(c0+c)*NK + k];
    kdcy[c] = lam*accy[c] + omlam*yim[(size_t)(c0+c)*NK + k];
  }

  #pragma unroll
  for (int jx = 0; jx < JW; ++jx){
    int ox = ix[jx]*GRID_N;
    #pragma unroll
    for (int jy = 0; jy < JW; ++jy){
      float w2 = wx[jx]*wy[jy];
      size_t o = (size_t)(ox + iy[jy]);
      #pragma unroll
      for (int c = 0; c < G; ++c){
        float* dst = HT + ((size_t)c*PLANE + o)*2;
        atomicAdd(dst,   w2*kdcx[c]);
        atomicAdd(dst+1, w2*kdcy[c]);
      }
    }
  }
}

// crop, apodize, conj(smaps) coil-combine; ACCUMULATES into out
template<int G>
__global__ void k_final(const cplx* __restrict__ Bg, const float* __restrict__ sr,
                        const float* __restrict__ si, const float* __restrict__ sc,
                        float* __restrict__ out, int c0, int pairs){
  int idx = blockIdx.x*blockDim.x + threadIdx.x;   // y*256+x
  if (idx >= IM_N*IM_N) return;
  int y = idx >> 8, x = idx & 255;
  float s2 = sc[y]*sc[x];
  float ax = 0.f, ay = 0.f;
  #pragma unroll
  for (int c = 0; c < G; ++c){
    cplx v = Bg[(size_t)c*PLANE + y*GRID_N + x];
    int gi = ((c0 + c) << 16) | idx;
    float rr = sr[gi], ii = si[gi];
    ax += rr*v.x + ii*v.y;      // conj(s)*v real
    ay += rr*v.y - ii*v.x;      // conj(s)*v imag
  }
  if (pairs){
    out[idx*2]   += ax * s2;
    out[idx*2+1] += ay * s2;
  } else {
    out[idx]     += ax * s2;    // harness stores real part only
  }
}

template<int G>
static void run_pass(const float* ximg, const float* yre, const float* yim,
                     const float* sre, const float* sim, const float* ktraj,
                     const float* lraw, const float* sc,
                     cplx* A, cplx* Bb, float* out, int c0, int pairs,
                     hipStream_t stream){
  const int n4 = G*PLANE*2/4;  // float4 count of one grid buffer

  k_zero4<<<(n4+255)/256,256,0,stream>>>((float4*)A, n4);
  k_fill<G><<<(G*IM_N*IM_N+255)/256,256,0,stream>>>(ximg, sre, sim, sc, A, c0);

  // forward fft2 / 512:  rows over x, transpose, rows over y  -> Bb = kg^T
  k_fft_rows<-1><<<G*GRID_N,256,0,stream>>>(A, 1.0f);
  k_transpose<<<dim3(16,16,G),dim3(32,8),0,stream>>>(A, Bb);
  k_fft_rows<-1><<<G*GRID_N,256,0,stream>>>(Bb, 1.0f/(float)GRID_N);

  // gather / lambda-blend / scatter into A = HT (x-major, interleaved floats)
  k_zero4<<<(n4+255)/256,256,0,stream>>>((float4*)A, n4);
  k_gather_scatter<G><<<(NK+255)/256,256,0,stream>>>(ktraj, yre, yim, lraw, Bb,
                                                    (float*)A, c0);

  // adjoint ifft2 * 512: rows over y, transpose, rows over x -> Bb = img [y][x]
  k_fft_rows<+1><<<G*GRID_N,256,0,stream>>>(A, 1.0f);
  k_transpose<<<dim3(16,16,G),dim3(32,8),0,stream>>>(A, Bb);
  k_fft_rows<+1><<<G*GRID_N,256,0,stream>>>(Bb, 1.0f/(float)GRID_N);

  k_final<G><<<(IM_N*IM_N+255)/256,256,0,stream>>>(Bb, sre, sim, sc, out, c0, pairs);
}

extern "C" void kernel_launch(void* const* d_in, const int* in_sizes, int n_in,
                              void* d_out, int out_size, void* d_ws, size_t ws_size,
                              hipStream_t stream) {
  const float* ximg  = (const float*)d_in[0];
  const float* yre   = (const float*)d_in[1];
  const float* yim   = (const float*)d_in[2];
  const float* sre   = (const float*)d_in[3];
  const float* sim   = (const float*)d_in[4];
  const float* ktraj = (const float*)d_in[5];
  const float* lraw  = (const float*)d_in[6];
  float* out = (float*)d_out;

  char* ws = (char*)d_ws;
  float* sc = (float*)ws;                       // 256 floats, padded to 4 KB
  const size_t plane_b = (size_t)PLANE*sizeof(cplx);   // 2 MB per coil plane

  // pick largest coil-group whose two grid buffers fit in the workspace
  int G = 8;
  while (G > 1 && (4096 + 2*(size_t)G*plane_b) > ws_size) G >>= 1;

  cplx* A  = (cplx*)(ws + 4096);
  cplx* Bb = (cplx*)(ws + 4096 + (size_t)G*plane_b);

  // harness stored the reference as float32: real-only (65536) or re/im pairs
  int pairs = (out_size >= 2*IM_N*IM_N) ? 1 : 0;

  k_sc_table<<<1,256,0,stream>>>(sc);
  k_zero1<<<(out_size+255)/256,256,0,stream>>>(out, out_size);

  switch (G){
    case 8:
      run_pass<8>(ximg,yre,yim,sre,sim,ktraj,lraw,sc,A,Bb,out,0,pairs,stream);
      break;
    case 4:
      for (int c0 = 0; c0 < NCOIL; c0 += 4)
        run_pass<4>(ximg,yre,yim,sre,sim,ktraj,lraw,sc,A,Bb,out,c0,pairs,stream);
      break;
    case 2:
      for (int c0 = 0; c0 < NCOIL; c0 += 2)
        run_pass<2>(ximg,yre,yim,sre,sim,ktraj,lraw,sc,A,Bb,out,c0,pairs,stream);
      break;
    default:
      for (int c0 = 0; c0 < NCOIL; c0 += 1)
        run_pass<1>(ximg,yre,yim,sre,sim,ktraj,lraw,sc,A,Bb,out,c0,pairs,stream);
      break;
  }
}

// Round 3
// 2263.204 us; speedup vs baseline: 1.3510x; 1.3510x over previous
//
#include <hip/hip_runtime.h>
#include <math.h>

#define GRID_N 512
#define IM_N   256
#define NCOIL  8
#define NK     131072
#define PLANE  (GRID_N*GRID_N)
#define JW     6
#define NENT   (NK*JW)
#define BETA_F 13.8551003f   /* pi*sqrt((6/2)^2*(2-0.5)^2 - 0.8) */
#define KSCALE 81.48733086305042f  /* 512/(2*pi) */

struct cplx { float x, y; };

__device__ __forceinline__ float bessel_i0f(float x){
  // Abramowitz & Stegun 9.8.1 / 9.8.2, rel err < 2e-7
  if (x < 3.75f){
    float t = x*(1.0f/3.75f); t = t*t;
    return 1.0f + t*(3.5156229f + t*(3.0899424f + t*(1.2067492f
           + t*(0.2659732f + t*(0.0360768f + t*0.0045813f)))));
  } else {
    float t = 3.75f/x;
    float p = 0.39894228f + t*(0.01328592f + t*(0.00225319f + t*(-0.00157565f
            + t*(0.00916281f + t*(-0.02057706f + t*(0.02635537f
            + t*(-0.01647633f + t*0.00392377f)))))));
    return p * __expf(x) * rsqrtf(x);
  }
}

__device__ __forceinline__ float kb_w(float u){   // 1-axis KB weight, |u|<=3
  float uu = u*(1.0f/3.0f);
  float q = fmaxf(1.0f - uu*uu, 0.0f);
  return bessel_i0f(BETA_F*sqrtf(q)) * (1.0f/6.0f);
}

// Kaiser-Bessel apodization correction row table sc[256]
__global__ void k_sc_table(float* sc){
  int i = threadIdx.x;
  if (i >= IM_N) return;
  float n  = (i - IM_N*0.5f) * (1.0f/GRID_N);
  float pj = 3.14159265358979f * (float)JW * n;
  float t  = BETA_F*BETA_F - pj*pj;
  float sp = sqrtf(fmaxf(t, 1e-12f));
  float sn = sqrtf(fmaxf(-t, 1e-12f));
  float ft = (t > 0.0f) ? (sinhf(sp)/sp) : (sinf(sn)/sn);
  float sc0 = sinhf(BETA_F)/BETA_F;
  sc[i] = sc0/ft;
}

__global__ void k_zero4(float4* p, int n4){
  int i = blockIdx.x*blockDim.x + threadIdx.x;
  if (i < n4) p[i] = make_float4(0.f,0.f,0.f,0.f);
}

__global__ void k_zero1(float* p, int n){
  int i = blockIdx.x*blockDim.x + threadIdx.x;
  if (i < n) p[i] = 0.f;
}

// coil_images * sc2 into padded 512^2 planar grids (A zeroed beforehand)
__global__ void k_fill(const float* __restrict__ ximg, const float* __restrict__ sr,
                       const float* __restrict__ si, const float* __restrict__ sc,
                       cplx* __restrict__ A){
  int idx = blockIdx.x*blockDim.x + threadIdx.x;   // c*65536 + y*256 + x
  if (idx >= NCOIL*IM_N*IM_N) return;
  int c = idx >> 16;
  int pix = idx & 65535;
  int y = pix >> 8, x = pix & 255;
  float v = ximg[pix] * sc[y]*sc[x];
  cplx o; o.x = v * sr[idx]; o.y = v * si[idx];
  A[(size_t)c*PLANE + y*GRID_N + x] = o;
}

// in-place 512-pt radix-2 FFT on each contiguous row; DIR=-1 fwd, +1 inv(unnorm)
template<int DIR>
__global__ void k_fft_rows(cplx* __restrict__ buf, float scale){
  __shared__ cplx lds[GRID_N];
  cplx* p = buf + (size_t)blockIdx.x * GRID_N;
  int tid = threadIdx.x;                       // 256 threads
  for (int i = tid; i < GRID_N; i += 256){
    int r = __brev((unsigned)i) >> 23;         // 9-bit reverse
    lds[r] = p[i];
  }
  __syncthreads();
  for (int half = 1; half < GRID_N; half <<= 1){
    int j = tid & (half-1);
    int k = ((tid & ~(half-1)) << 1) | j;
    float ang = (float)DIR * 3.14159265358979f * (float)j / (float)half;
    float sw, cw; __sincosf(ang, &sw, &cw);
    cplx u = lds[k];
    cplx v = lds[k+half];
    cplx t; t.x = v.x*cw - v.y*sw; t.y = v.x*sw + v.y*cw;
    lds[k].x      = u.x + t.x; lds[k].y      = u.y + t.y;
    lds[k+half].x = u.x - t.x; lds[k+half].y = u.y - t.y;
    __syncthreads();
  }
  for (int i = tid; i < GRID_N; i += 256){
    cplx v = lds[i]; v.x *= scale; v.y *= scale; p[i] = v;
  }
}

// 512x512 tile transpose per coil plane, out[X][Y] = in[Y][X]
__global__ void k_transpose(const cplx* __restrict__ in, cplx* __restrict__ out){
  __shared__ cplx tile[32][33];
  int c  = blockIdx.z;
  int x0 = blockIdx.x*32, y0 = blockIdx.y*32;
  const cplx* ip = in  + (size_t)c*PLANE;
  cplx*       op = out + (size_t)c*PLANE;
  int tx = threadIdx.x, ty = threadIdx.y;      // (32,8)
  for (int dy = 0; dy < 32; dy += 8)
    tile[ty+dy][tx] = ip[(size_t)(y0+ty+dy)*GRID_N + (x0+tx)];
  __syncthreads();
  for (int dy = 0; dy < 32; dy += 8)
    op[(size_t)(x0+ty+dy)*GRID_N + (y0+tx)] = tile[tx][ty+dy];
}

// planar [c][cell] -> coil-interleaved [cell][8 float2]  (fully coalesced)
__global__ void k_c2i(const float2* __restrict__ plan, float2* __restrict__ inter){
  int t = blockIdx.x*blockDim.x + threadIdx.x;
  if (t >= PLANE*NCOIL) return;
  int c = t & 7; int cell = t >> 3;
  inter[(size_t)cell*8 + c] = plan[(size_t)c*PLANE + cell];
}

// coil-interleaved [cell][8 float2] -> planar [c][cell]
__global__ void k_i2c(const float2* __restrict__ inter, float2* __restrict__ plan){
  int t = blockIdx.x*blockDim.x + threadIdx.x;
  if (t >= PLANE*NCOIL) return;
  int c = t & 7; int cell = t >> 3;
  plan[(size_t)c*PLANE + cell] = inter[(size_t)cell*8 + c];
}

// forward interp + lambda blend: thread = (sample, coil-pair)
__global__ __launch_bounds__(256) void k_fwd(
    const float* __restrict__ ktraj, const float* __restrict__ yre,
    const float* __restrict__ yim, const float* __restrict__ lraw,
    const float4* __restrict__ KTi4, float4* __restrict__ kdc4){
  int t = blockIdx.x*blockDim.x + threadIdx.x;
  if (t >= NK*4) return;
  int k = t >> 2, p = t & 3;

  int iy[JW], ix[JW]; float wy[JW], wx[JW];
  {
    float tm = ktraj[k] * KSCALE;
    int base = (int)floorf(tm - 3.0f);
    #pragma unroll
    for (int j = 1; j <= JW; ++j){
      int fidx = base + j;
      wy[j-1] = kb_w(tm - (float)fidx);
      iy[j-1] = fidx & (GRID_N-1);
    }
  }
  {
    float tm = ktraj[NK + k] * KSCALE;
    int base = (int)floorf(tm - 3.0f);
    #pragma unroll
    for (int j = 1; j <= JW; ++j){
      int fidx = base + j;
      wx[j-1] = kb_w(tm - (float)fidx);
      ix[j-1] = fidx & (GRID_N-1);
    }
  }

  float ax=0.f, ay=0.f, az=0.f, aw=0.f;
  #pragma unroll
  for (int jx = 0; jx < JW; ++jx){
    int ox = ix[jx]*GRID_N;
    #pragma unroll
    for (int jy = 0; jy < JW; ++jy){
      float w2 = wx[jx]*wy[jy];
      float4 v = KTi4[(size_t)(ox + iy[jy])*4 + p];
      ax += w2*v.x; ay += w2*v.y; az += w2*v.z; aw += w2*v.w;
    }
  }
  float lam = 1.0f/(1.0f + __expf(-lraw[0]));
  float oml = 1.0f - lam;
  int c0 = 2*p;
  float4 o;
  o.x = lam*ax + oml*yre[(size_t)c0*NK + k];
  o.y = lam*ay + oml*yim[(size_t)c0*NK + k];
  o.z = lam*az + oml*yre[(size_t)(c0+1)*NK + k];
  o.w = lam*aw + oml*yim[(size_t)(c0+1)*NK + k];
  kdc4[(size_t)k*4 + p] = o;
}

// histogram over x-base bins + per-sample rank
__global__ void k_hist(const float* __restrict__ ktraj, unsigned* __restrict__ hist,
                       unsigned* __restrict__ rank){
  int k = blockIdx.x*blockDim.x + threadIdx.x;
  if (k >= NK) return;
  float tmx = ktraj[NK + k] * KSCALE;
  int bx = (int)floorf(tmx - 3.0f);
  rank[k] = atomicAdd(&hist[bx & (GRID_N-1)], 1u);
}

// column counts + exclusive scan (single block of 512)
__global__ void k_scan512(const unsigned* __restrict__ hist, unsigned* __restrict__ colOff){
  __shared__ unsigned s[GRID_N];
  int t = threadIdx.x;
  unsigned v = 0;
  #pragma unroll
  for (int d = 1; d <= JW; ++d) v += hist[(t - d) & (GRID_N-1)];
  s[t] = v;
  __syncthreads();
  for (int off = 1; off < GRID_N; off <<= 1){
    unsigned add = (t >= off) ? s[t - off] : 0u;
    __syncthreads();
    s[t] += add;
    __syncthreads();
  }
  colOff[t] = (t == 0) ? 0u : s[t-1];
}

// place (column, sample) entries at closed-form positions (no contention)
__global__ void k_fill_entries(const float* __restrict__ ktraj,
                               const unsigned* __restrict__ rank,
                               const unsigned* __restrict__ hist,
                               const unsigned* __restrict__ colOff,
                               unsigned* __restrict__ entries){
  int k = blockIdx.x*blockDim.x + threadIdx.x;
  if (k >= NK) return;
  float tmx = ktraj[NK + k] * KSCALE;
  int bx = (int)floorf(tmx - 3.0f);
  unsigned r = rank[k];
  unsigned run = 0;
  #pragma unroll
  for (int j = 1; j <= JW; ++j){
    int cc = (bx + j) & (GRID_N-1);
    entries[colOff[cc] + run + r] = (unsigned)k;
    run += hist[cc];
  }
}

// adjoint gridding, owner-computes: block = x-column, thread owns 2 y-cells x 8 coils
__global__ __launch_bounds__(256) void k_col_accum(
    const float* __restrict__ ktraj, const unsigned* __restrict__ entries,
    const unsigned* __restrict__ colOff, const float4* __restrict__ kdc4,
    float4* __restrict__ HTi4){
  __shared__ unsigned s_k[256];
  __shared__ float s_ty[256], s_wx[256];
  const int c = blockIdx.x;
  const int tid = threadIdx.x;
  unsigned beg = colOff[c];
  unsigned end = (c < GRID_N-1) ? colOff[c+1] : (unsigned)NENT;

  float4 acc0[4], acc1[4];
  #pragma unroll
  for (int p = 0; p < 4; ++p){
    acc0[p] = make_float4(0.f,0.f,0.f,0.f);
    acc1[p] = make_float4(0.f,0.f,0.f,0.f);
  }
  const int y0 = tid, y1 = tid + 256;

  for (unsigned base = beg; base < end; base += 256){
    unsigned rem = end - base;
    int n = (rem > 256u) ? 256 : (int)rem;
    __syncthreads();
    if (tid < n){
      unsigned kk = entries[base + tid];
      float tmx = ktraj[NK + kk] * KSCALE;
      int bx = (int)floorf(tmx - 3.0f);
      int j = (c - bx) & (GRID_N-1);          // guaranteed in [1,6]
      s_wx[tid] = kb_w(tmx - (float)(bx + j));
      s_k[tid]  = kk;
      s_ty[tid] = ktraj[kk] * KSCALE;
    }
    __syncthreads();
    for (int i = 0; i < n; ++i){
      float tmy = s_ty[i];
      int by = (int)floorf(tmy - 3.0f);
      int j0 = (y0 - by) & (GRID_N-1);
      int j1 = (y1 - by) & (GRID_N-1);
      bool h0 = (j0 >= 1) && (j0 <= JW);
      bool h1 = (j1 >= 1) && (j1 <= JW);
      if (!(h0 || h1)) continue;
      float wxv = s_wx[i];
      unsigned kk = s_k[i];
      if (h0){
        float w = wxv * kb_w(tmy - (float)(by + j0));
        #pragma unroll
        for (int p = 0; p < 4; ++p){
          float4 v = kdc4[(size_t)kk*4 + p];
          acc0[p].x += w*v.x; acc0[p].y += w*v.y;
          acc0[p].z += w*v.z; acc0[p].w += w*v.w;
        }
      }
      if (h1){
        float w = wxv * kb_w(tmy - (float)(by + j1));
        #pragma unroll
        for (int p = 0; p < 4; ++p){
          float4 v = kdc4[(size_t)kk*4 + p];
          acc1[p].x += w*v.x; acc1[p].y += w*v.y;
          acc1[p].z += w*v.z; acc1[p].w += w*v.w;
        }
      }
    }
  }
  #pragma unroll
  for (int p = 0; p < 4; ++p){
    HTi4[((size_t)c*GRID_N + y0)*4 + p] = acc0[p];
    HTi4[((size_t)c*GRID_N + y1)*4 + p] = acc1[p];
  }
}

// crop, apodize, conj(smaps) coil-combine; ACCUMULATES into out
__global__ void k_final(const cplx* __restrict__ Bg, const float* __restrict__ sr,
                        const float* __restrict__ si, const float* __restrict__ sc,
                        float* __restrict__ out, int pairs){
  int idx = blockIdx.x*blockDim.x + threadIdx.x;   // y*256+x
  if (idx >= IM_N*IM_N) return;
  int y = idx >> 8, x = idx & 255;
  float s2 = sc[y]*sc[x];
  float ax = 0.f, ay = 0.f;
  #pragma unroll
  for (int c = 0; c < NCOIL; ++c){
    cplx v = Bg[(size_t)c*PLANE + y*GRID_N + x];
    int gi = (c << 16) | idx;
    float rr = sr[gi], ii = si[gi];
    ax += rr*v.x + ii*v.y;      // conj(s)*v real
    ay += rr*v.y - ii*v.x;      // conj(s)*v imag
  }
  if (pairs){
    out[idx*2]   += ax * s2;
    out[idx*2+1] += ay * s2;
  } else {
    out[idx]     += ax * s2;
  }
}

// ---------------- fallback (round-2 validated fused atomic path) -------------
__global__ void k_gather_scatter_fb(const float* __restrict__ ktraj,
                                    const float* __restrict__ yre,
                                    const float* __restrict__ yim,
                                    const float* __restrict__ lraw,
                                    const cplx* __restrict__ KT,
                                    float* __restrict__ HT){
  int k = blockIdx.x*blockDim.x + threadIdx.x;
  if (k >= NK) return;
  float lam   = 1.0f/(1.0f + __expf(-lraw[0]));
  float omlam = 1.0f - lam;
  int iy[JW], ix[JW]; float wy[JW], wx[JW];
  {
    float tm = ktraj[k] * KSCALE;
    int base = (int)floorf(tm - 3.0f);
    #pragma unroll
    for (int j = 1; j <= JW; ++j){
      wy[j-1] = kb_w(tm - (float)(base+j));
      iy[j-1] = (base+j) & (GRID_N-1);
    }
  }
  {
    float tm = ktraj[NK + k] * KSCALE;
    int base = (int)floorf(tm - 3.0f);
    #pragma unroll
    for (int j = 1; j <= JW; ++j){
      wx[j-1] = kb_w(tm - (float)(base+j));
      ix[j-1] = (base+j) & (GRID_N-1);
    }
  }
  float accx[NCOIL], accy[NCOIL];
  #pragma unroll
  for (int c = 0; c < NCOIL; ++c){ accx[c]=0.f; accy[c]=0.f; }
  #pragma unroll
  for (int jx = 0; jx < JW; ++jx){
    int ox = ix[jx]*GRID_N;
    #pragma unroll
    for (int jy = 0; jy < JW; ++jy){
      float w2 = wx[jx]*wy[jy];
      size_t o = (size_t)(ox + iy[jy]);
      #pragma unroll
      for (int c = 0; c < NCOIL; ++c){
        cplx v = KT[(size_t)c*PLANE + o];
        accx[c] += w2*v.x; accy[c] += w2*v.y;
      }
    }
  }
  float kdx[NCOIL], kdy[NCOIL];
  #pragma unroll
  for (int c = 0; c < NCOIL; ++c){
    kdx[c] = lam*accx[c] + omlam*yre[(size_t)c*NK + k];
    kdy[c] = lam*accy[c] + omlam*yim[(size_t)c*NK + k];
  }
  #pragma unroll
  for (int jx = 0; jx < JW; ++jx){
    int ox = ix[jx]*GRID_N;
    #pragma unroll
    for (int jy = 0; jy < JW; ++jy){
      float w2 = wx[jx]*wy[jy];
      size_t o = (size_t)(ox + iy[jy]);
      #pragma unroll
      for (int c = 0; c < NCOIL; ++c){
        float* dst = HT + ((size_t)c*PLANE + o)*2;
        atomicAdd(dst,   w2*kdx[c]);
        atomicAdd(dst+1, w2*kdy[c]);
      }
    }
  }
}

extern "C" void kernel_launch(void* const* d_in, const int* in_sizes, int n_in,
                              void* d_out, int out_size, void* d_ws, size_t ws_size,
                              hipStream_t stream) {
  const float* ximg  = (const float*)d_in[0];
  const float* yre   = (const float*)d_in[1];
  const float* yim   = (const float*)d_in[2];
  const float* sre   = (const float*)d_in[3];
  const float* sim   = (const float*)d_in[4];
  const float* ktraj = (const float*)d_in[5];
  const float* lraw  = (const float*)d_in[6];
  float* out = (float*)d_out;

  char* ws = (char*)d_ws;
  const size_t REG = 16777216;                 // one planar grid: 512*512*8B*8
  int pairs = (out_size >= 2*IM_N*IM_N) ? 1 : 0;

  // primary layout (50.34 MB):
  //   [0, REG)      A planar; reused after fwd-transpose for kdc/rank/entries
  //   [REG, 2REG)   B planar
  //   [2REG, 3REG)  KTi interleaved; reused as HTi by k_col_accum
  //   [3REG, ...)   sc (1KB), hist (2KB), colOff (2KB)
  const size_t need = 3*REG + 4096 + 2048 + 2048;

  if (ws_size >= need){
    cplx*     A     = (cplx*)ws;
    cplx*     Bb    = (cplx*)(ws + REG);
    float4*   KTi4  = (float4*)(ws + 2*REG);
    float*    sc    = (float*)(ws + 3*REG);
    unsigned* hist  = (unsigned*)(ws + 3*REG + 4096);
    unsigned* colOff= (unsigned*)(ws + 3*REG + 4096 + 2048);
    float4*   kdc4  = (float4*)ws;                       // overlays dead A
    unsigned* rank  = (unsigned*)(ws + (size_t)NK*16*4); // + 8,388,608
    unsigned* entries = (unsigned*)(ws + (size_t)NK*16*4 + (size_t)NK*4);

    const int n4 = NCOIL*PLANE*2/4;

    k_sc_table<<<1,256,0,stream>>>(sc);
    k_zero4<<<(n4+255)/256,256,0,stream>>>((float4*)A, n4);
    k_fill<<<(NCOIL*IM_N*IM_N+255)/256,256,0,stream>>>(ximg, sre, sim, sc, A);

    // fwd fft2/512: rows over x, transpose, rows over y -> Bb = kg^T planar [x][y]
    k_fft_rows<-1><<<NCOIL*GRID_N,256,0,stream>>>(A, 1.0f);
    k_transpose<<<dim3(16,16,NCOIL),dim3(32,8),0,stream>>>(A, Bb);
    k_fft_rows<-1><<<NCOIL*GRID_N,256,0,stream>>>(Bb, 1.0f/(float)GRID_N);

    k_c2i<<<(PLANE*NCOIL+255)/256,256,0,stream>>>((const float2*)Bb, (float2*)KTi4);

    // forward interp + blend -> kdc (A region is dead now)
    k_fwd<<<(NK*4+255)/256,256,0,stream>>>(ktraj, yre, yim, lraw, KTi4, kdc4);

    // column binning (131K int atomics total)
    k_zero1<<<2,256,0,stream>>>((float*)hist, GRID_N);
    k_hist<<<NK/256,256,0,stream>>>(ktraj, hist, rank);
    k_scan512<<<1,GRID_N,0,stream>>>(hist, colOff);
    k_fill_entries<<<NK/256,256,0,stream>>>(ktraj, rank, hist, colOff, entries);

    // adjoint gridding, atomic-free; writes HTi over the dead KTi region
    k_col_accum<<<GRID_N,256,0,stream>>>(ktraj, entries, colOff, kdc4, KTi4);

    k_i2c<<<(PLANE*NCOIL+255)/256,256,0,stream>>>((const float2*)KTi4, (float2*)Bb);

    // adjoint ifft2*512: rows over y, transpose, rows over x -> A = img [y][x]
    k_fft_rows<+1><<<NCOIL*GRID_N,256,0,stream>>>(Bb, 1.0f);
    k_transpose<<<dim3(16,16,NCOIL),dim3(32,8),0,stream>>>(Bb, A);
    k_fft_rows<+1><<<NCOIL*GRID_N,256,0,stream>>>(A, 1.0f/(float)GRID_N);

    k_zero1<<<(out_size+255)/256,256,0,stream>>>(out, out_size);
    k_final<<<(IM_N*IM_N+255)/256,256,0,stream>>>(A, sre, sim, sc, out, pairs);
  } else {
    // fallback: round-2 validated path (needs 33.6 MB)
    float* sc = (float*)ws;
    cplx*  A  = (cplx*)(ws + 4096);
    cplx*  Bb = (cplx*)(ws + 4096 + REG);
    const int n4 = NCOIL*PLANE*2/4;

    k_sc_table<<<1,256,0,stream>>>(sc);
    k_zero4<<<(n4+255)/256,256,0,stream>>>((float4*)A, n4);
    k_fill<<<(NCOIL*IM_N*IM_N+255)/256,256,0,stream>>>(ximg, sre, sim, sc, A);
    k_fft_rows<-1><<<NCOIL*GRID_N,256,0,stream>>>(A, 1.0f);
    k_transpose<<<dim3(16,16,NCOIL),dim3(32,8),0,stream>>>(A, Bb);
    k_fft_rows<-1><<<NCOIL*GRID_N,256,0,stream>>>(Bb, 1.0f/(float)GRID_N);
    k_zero4<<<(n4+255)/256,256,0,stream>>>((float4*)A, n4);
    k_gather_scatter_fb<<<(NK+255)/256,256,0,stream>>>(ktraj, yre, yim, lraw, Bb, (float*)A);
    k_fft_rows<+1><<<NCOIL*GRID_N,256,0,stream>>>(A, 1.0f);
    k_transpose<<<dim3(16,16,NCOIL),dim3(32,8),0,stream>>>(A, Bb);
    k_fft_rows<+1><<<NCOIL*GRID_N,256,0,stream>>>(Bb, 1.0f/(float)GRID_N);
    k_zero1<<<(out_size+255)/256,256,0,stream>>>(out, out_size);
    k_final<<<(IM_N*IM_N+255)/256,256,0,stream>>>(Bb, sre, sim, sc, out, pairs);
  }
}

// Round 4
// 976.455 us; speedup vs baseline: 3.1312x; 2.3178x over previous
//
#include <hip/hip_runtime.h>
#include <math.h>

#define GRID_N 512
#define IM_N   256
#define NCOIL  8
#define NK     131072
#define PLANE  (GRID_N*GRID_N)
#define JW     6
#define NENT   (NK*JW)
#define BETA_F 13.8551003f   /* pi*sqrt((6/2)^2*(2-0.5)^2 - 0.8) */
#define KSCALE 81.48733086305042f  /* 512/(2*pi) */

struct cplx { float x, y; };

__device__ __forceinline__ float bessel_i0f(float x){
  // Abramowitz & Stegun 9.8.1 / 9.8.2, rel err < 2e-7
  if (x < 3.75f){
    float t = x*(1.0f/3.75f); t = t*t;
    return 1.0f + t*(3.5156229f + t*(3.0899424f + t*(1.2067492f
           + t*(0.2659732f + t*(0.0360768f + t*0.0045813f)))));
  } else {
    float t = 3.75f/x;
    float p = 0.39894228f + t*(0.01328592f + t*(0.00225319f + t*(-0.00157565f
            + t*(0.00916281f + t*(-0.02057706f + t*(0.02635537f
            + t*(-0.01647633f + t*0.00392377f)))))));
    return p * __expf(x) * rsqrtf(x);
  }
}

__device__ __forceinline__ float kb_w(float u){   // 1-axis KB weight, |u|<=3
  float uu = u*(1.0f/3.0f);
  float q = fmaxf(1.0f - uu*uu, 0.0f);
  return bessel_i0f(BETA_F*sqrtf(q)) * (1.0f/6.0f);
}

// Kaiser-Bessel apodization correction row table sc[256]
__global__ void k_sc_table(float* sc){
  int i = threadIdx.x;
  if (i >= IM_N) return;
  float n  = (i - IM_N*0.5f) * (1.0f/GRID_N);
  float pj = 3.14159265358979f * (float)JW * n;
  float t  = BETA_F*BETA_F - pj*pj;
  float sp = sqrtf(fmaxf(t, 1e-12f));
  float sn = sqrtf(fmaxf(-t, 1e-12f));
  float ft = (t > 0.0f) ? (sinhf(sp)/sp) : (sinf(sn)/sn);
  float sc0 = sinhf(BETA_F)/BETA_F;
  sc[i] = sc0/ft;
}

__global__ void k_zero4(float4* p, int n4){
  int i = blockIdx.x*blockDim.x + threadIdx.x;
  if (i < n4) p[i] = make_float4(0.f,0.f,0.f,0.f);
}

__global__ void k_zero1(float* p, int n){
  int i = blockIdx.x*blockDim.x + threadIdx.x;
  if (i < n) p[i] = 0.f;
}

// coil_images * sc2 into padded 512^2 planar grids (A zeroed beforehand)
__global__ void k_fill(const float* __restrict__ ximg, const float* __restrict__ sr,
                       const float* __restrict__ si, const float* __restrict__ sc,
                       cplx* __restrict__ A){
  int idx = blockIdx.x*blockDim.x + threadIdx.x;   // c*65536 + y*256 + x
  if (idx >= NCOIL*IM_N*IM_N) return;
  int c = idx >> 16;
  int pix = idx & 65535;
  int y = pix >> 8, x = pix & 255;
  float v = ximg[pix] * sc[y]*sc[x];
  cplx o; o.x = v * sr[idx]; o.y = v * si[idx];
  A[(size_t)c*PLANE + y*GRID_N + x] = o;
}

// in-place 512-pt radix-2 FFT on each contiguous row; DIR=-1 fwd, +1 inv(unnorm)
template<int DIR>
__global__ void k_fft_rows(cplx* __restrict__ buf, float scale){
  __shared__ cplx lds[GRID_N];
  cplx* p = buf + (size_t)blockIdx.x * GRID_N;
  int tid = threadIdx.x;                       // 256 threads
  for (int i = tid; i < GRID_N; i += 256){
    int r = __brev((unsigned)i) >> 23;         // 9-bit reverse
    lds[r] = p[i];
  }
  __syncthreads();
  for (int half = 1; half < GRID_N; half <<= 1){
    int j = tid & (half-1);
    int k = ((tid & ~(half-1)) << 1) | j;
    float ang = (float)DIR * 3.14159265358979f * (float)j / (float)half;
    float sw, cw; __sincosf(ang, &sw, &cw);
    cplx u = lds[k];
    cplx v = lds[k+half];
    cplx t; t.x = v.x*cw - v.y*sw; t.y = v.x*sw + v.y*cw;
    lds[k].x      = u.x + t.x; lds[k].y      = u.y + t.y;
    lds[k+half].x = u.x - t.x; lds[k+half].y = u.y - t.y;
    __syncthreads();
  }
  for (int i = tid; i < GRID_N; i += 256){
    cplx v = lds[i]; v.x *= scale; v.y *= scale; p[i] = v;
  }
}

// 512x512 tile transpose per coil plane, out[X][Y] = in[Y][X]
__global__ void k_transpose(const cplx* __restrict__ in, cplx* __restrict__ out){
  __shared__ cplx tile[32][33];
  int c  = blockIdx.z;
  int x0 = blockIdx.x*32, y0 = blockIdx.y*32;
  const cplx* ip = in  + (size_t)c*PLANE;
  cplx*       op = out + (size_t)c*PLANE;
  int tx = threadIdx.x, ty = threadIdx.y;      // (32,8)
  for (int dy = 0; dy < 32; dy += 8)
    tile[ty+dy][tx] = ip[(size_t)(y0+ty+dy)*GRID_N + (x0+tx)];
  __syncthreads();
  for (int dy = 0; dy < 32; dy += 8)
    op[(size_t)(x0+ty+dy)*GRID_N + (y0+tx)] = tile[tx][ty+dy];
}

// planar [c][cell] -> coil-interleaved [cell][8 float2]  (fully coalesced)
__global__ void k_c2i(const float2* __restrict__ plan, float2* __restrict__ inter){
  int t = blockIdx.x*blockDim.x + threadIdx.x;
  if (t >= PLANE*NCOIL) return;
  int c = t & 7; int cell = t >> 3;
  inter[(size_t)cell*8 + c] = plan[(size_t)c*PLANE + cell];
}

// coil-interleaved [cell][8 float2] -> planar [c][cell]
__global__ void k_i2c(const float2* __restrict__ inter, float2* __restrict__ plan){
  int t = blockIdx.x*blockDim.x + threadIdx.x;
  if (t >= PLANE*NCOIL) return;
  int c = t & 7; int cell = t >> 3;
  plan[(size_t)c*PLANE + cell] = inter[(size_t)cell*8 + c];
}

// forward interp + lambda blend: thread = (sample, coil-pair)
__global__ __launch_bounds__(256) void k_fwd(
    const float* __restrict__ ktraj, const float* __restrict__ yre,
    const float* __restrict__ yim, const float* __restrict__ lraw,
    const float4* __restrict__ KTi4, float4* __restrict__ kdc4){
  int t = blockIdx.x*blockDim.x + threadIdx.x;
  if (t >= NK*4) return;
  int k = t >> 2, p = t & 3;

  int iy[JW], ix[JW]; float wy[JW], wx[JW];
  {
    float tm = ktraj[k] * KSCALE;
    int base = (int)floorf(tm - 3.0f);
    #pragma unroll
    for (int j = 1; j <= JW; ++j){
      int fidx = base + j;
      wy[j-1] = kb_w(tm - (float)fidx);
      iy[j-1] = fidx & (GRID_N-1);
    }
  }
  {
    float tm = ktraj[NK + k] * KSCALE;
    int base = (int)floorf(tm - 3.0f);
    #pragma unroll
    for (int j = 1; j <= JW; ++j){
      int fidx = base + j;
      wx[j-1] = kb_w(tm - (float)fidx);
      ix[j-1] = fidx & (GRID_N-1);
    }
  }

  float ax=0.f, ay=0.f, az=0.f, aw=0.f;
  #pragma unroll
  for (int jx = 0; jx < JW; ++jx){
    int ox = ix[jx]*GRID_N;
    #pragma unroll
    for (int jy = 0; jy < JW; ++jy){
      float w2 = wx[jx]*wy[jy];
      float4 v = KTi4[(size_t)(ox + iy[jy])*4 + p];
      ax += w2*v.x; ay += w2*v.y; az += w2*v.z; aw += w2*v.w;
    }
  }
  float lam = 1.0f/(1.0f + __expf(-lraw[0]));
  float oml = 1.0f - lam;
  int c0 = 2*p;
  float4 o;
  o.x = lam*ax + oml*yre[(size_t)c0*NK + k];
  o.y = lam*ay + oml*yim[(size_t)c0*NK + k];
  o.z = lam*az + oml*yre[(size_t)(c0+1)*NK + k];
  o.w = lam*aw + oml*yim[(size_t)(c0+1)*NK + k];
  kdc4[(size_t)k*4 + p] = o;
}

// histogram over x-base bins + per-sample rank
__global__ void k_hist(const float* __restrict__ ktraj, unsigned* __restrict__ hist,
                       unsigned* __restrict__ rank){
  int k = blockIdx.x*blockDim.x + threadIdx.x;
  if (k >= NK) return;
  float tmx = ktraj[NK + k] * KSCALE;
  int bx = (int)floorf(tmx - 3.0f);
  rank[k] = atomicAdd(&hist[bx & (GRID_N-1)], 1u);
}

// column counts + exclusive scan (single block of 512)
__global__ void k_scan512(const unsigned* __restrict__ hist, unsigned* __restrict__ colOff){
  __shared__ unsigned s[GRID_N];
  int t = threadIdx.x;
  unsigned v = 0;
  #pragma unroll
  for (int d = 1; d <= JW; ++d) v += hist[(t - d) & (GRID_N-1)];
  s[t] = v;
  __syncthreads();
  for (int off = 1; off < GRID_N; off <<= 1){
    unsigned add = (t >= off) ? s[t - off] : 0u;
    __syncthreads();
    s[t] += add;
    __syncthreads();
  }
  colOff[t] = (t == 0) ? 0u : s[t-1];
}

// place (column, sample) entries at closed-form positions (no contention)
__global__ void k_fill_entries(const float* __restrict__ ktraj,
                               const unsigned* __restrict__ rank,
                               const unsigned* __restrict__ hist,
                               const unsigned* __restrict__ colOff,
                               unsigned* __restrict__ entries){
  int k = blockIdx.x*blockDim.x + threadIdx.x;
  if (k >= NK) return;
  float tmx = ktraj[NK + k] * KSCALE;
  int bx = (int)floorf(tmx - 3.0f);
  unsigned r = rank[k];
  unsigned run = 0;
  #pragma unroll
  for (int j = 1; j <= JW; ++j){
    int cc = (bx + j) & (GRID_N-1);
    entries[colOff[cc] + run + r] = (unsigned)k;
    run += hist[cc];
  }
}

// adjoint gridding: block = x-column; threads parallel over entries,
// accumulate into 32KB LDS tile acc[q][y] via ds_add_f32 (no global atomics)
__global__ __launch_bounds__(256) void k_col_accum(
    const float* __restrict__ ktraj, const unsigned* __restrict__ entries,
    const unsigned* __restrict__ colOff, const float4* __restrict__ kdc4,
    float4* __restrict__ HTi4){
  __shared__ float acc[16*GRID_N];             // [q][y], q = coil*2+reim
  const int c = blockIdx.x;
  const int tid = threadIdx.x;
  for (int i = tid; i < 16*GRID_N; i += 256) acc[i] = 0.f;
  __syncthreads();

  unsigned beg = colOff[c];
  unsigned end = (c < GRID_N-1) ? colOff[c+1] : (unsigned)NENT;

  for (unsigned e = beg + tid; e < end; e += 256){
    unsigned kk = entries[e];
    float tmx = ktraj[NK + kk] * KSCALE;
    int bx = (int)floorf(tmx - 3.0f);
    int j = (c - bx) & (GRID_N-1);             // in [1,6] by construction
    float wx = kb_w(tmx - (float)(bx + j));
    float tmy = ktraj[kk] * KSCALE;
    int by = (int)floorf(tmy - 3.0f);
    float4 v0 = kdc4[(size_t)kk*4 + 0];
    float4 v1 = kdc4[(size_t)kk*4 + 1];
    float4 v2 = kdc4[(size_t)kk*4 + 2];
    float4 v3 = kdc4[(size_t)kk*4 + 3];
    #pragma unroll
    for (int jy = 1; jy <= JW; ++jy){
      int y = (by + jy) & (GRID_N-1);
      float w = wx * kb_w(tmy - (float)(by + jy));
      atomicAdd(&acc[ 0*GRID_N + y], w*v0.x);
      atomicAdd(&acc[ 1*GRID_N + y], w*v0.y);
      atomicAdd(&acc[ 2*GRID_N + y], w*v0.z);
      atomicAdd(&acc[ 3*GRID_N + y], w*v0.w);
      atomicAdd(&acc[ 4*GRID_N + y], w*v1.x);
      atomicAdd(&acc[ 5*GRID_N + y], w*v1.y);
      atomicAdd(&acc[ 6*GRID_N + y], w*v1.z);
      atomicAdd(&acc[ 7*GRID_N + y], w*v1.w);
      atomicAdd(&acc[ 8*GRID_N + y], w*v2.x);
      atomicAdd(&acc[ 9*GRID_N + y], w*v2.y);
      atomicAdd(&acc[10*GRID_N + y], w*v2.z);
      atomicAdd(&acc[11*GRID_N + y], w*v2.w);
      atomicAdd(&acc[12*GRID_N + y], w*v3.x);
      atomicAdd(&acc[13*GRID_N + y], w*v3.y);
      atomicAdd(&acc[14*GRID_N + y], w*v3.z);
      atomicAdd(&acc[15*GRID_N + y], w*v3.w);
    }
  }
  __syncthreads();

  // dense writeback: 512 cells x 4 float4
  for (int i = tid; i < GRID_N*4; i += 256){   // i = y*4 + p
    int y = i >> 2, p = i & 3;
    float4 o;
    o.x = acc[(4*p+0)*GRID_N + y];
    o.y = acc[(4*p+1)*GRID_N + y];
    o.z = acc[(4*p+2)*GRID_N + y];
    o.w = acc[(4*p+3)*GRID_N + y];
    HTi4[((size_t)c*GRID_N + y)*4 + p] = o;
  }
}

// crop, apodize, conj(smaps) coil-combine; ACCUMULATES into out
__global__ void k_final(const cplx* __restrict__ Bg, const float* __restrict__ sr,
                        const float* __restrict__ si, const float* __restrict__ sc,
                        float* __restrict__ out, int pairs){
  int idx = blockIdx.x*blockDim.x + threadIdx.x;   // y*256+x
  if (idx >= IM_N*IM_N) return;
  int y = idx >> 8, x = idx & 255;
  float s2 = sc[y]*sc[x];
  float ax = 0.f, ay = 0.f;
  #pragma unroll
  for (int c = 0; c < NCOIL; ++c){
    cplx v = Bg[(size_t)c*PLANE + y*GRID_N + x];
    int gi = (c << 16) | idx;
    float rr = sr[gi], ii = si[gi];
    ax += rr*v.x + ii*v.y;      // conj(s)*v real
    ay += rr*v.y - ii*v.x;      // conj(s)*v imag
  }
  if (pairs){
    out[idx*2]   += ax * s2;
    out[idx*2+1] += ay * s2;
  } else {
    out[idx]     += ax * s2;
  }
}

// ---------------- fallback (round-2 validated fused atomic path) -------------
__global__ void k_gather_scatter_fb(const float* __restrict__ ktraj,
                                    const float* __restrict__ yre,
                                    const float* __restrict__ yim,
                                    const float* __restrict__ lraw,
                                    const cplx* __restrict__ KT,
                                    float* __restrict__ HT){
  int k = blockIdx.x*blockDim.x + threadIdx.x;
  if (k >= NK) return;
  float lam   = 1.0f/(1.0f + __expf(-lraw[0]));
  float omlam = 1.0f - lam;
  int iy[JW], ix[JW]; float wy[JW], wx[JW];
  {
    float tm = ktraj[k] * KSCALE;
    int base = (int)floorf(tm - 3.0f);
    #pragma unroll
    for (int j = 1; j <= JW; ++j){
      wy[j-1] = kb_w(tm - (float)(base+j));
      iy[j-1] = (base+j) & (GRID_N-1);
    }
  }
  {
    float tm = ktraj[NK + k] * KSCALE;
    int base = (int)floorf(tm - 3.0f);
    #pragma unroll
    for (int j = 1; j <= JW; ++j){
      wx[j-1] = kb_w(tm - (float)(base+j));
      ix[j-1] = (base+j) & (GRID_N-1);
    }
  }
  float accx[NCOIL], accy[NCOIL];
  #pragma unroll
  for (int c = 0; c < NCOIL; ++c){ accx[c]=0.f; accy[c]=0.f; }
  #pragma unroll
  for (int jx = 0; jx < JW; ++jx){
    int ox = ix[jx]*GRID_N;
    #pragma unroll
    for (int jy = 0; jy < JW; ++jy){
      float w2 = wx[jx]*wy[jy];
      size_t o = (size_t)(ox + iy[jy]);
      #pragma unroll
      for (int c = 0; c < NCOIL; ++c){
        cplx v = KT[(size_t)c*PLANE + o];
        accx[c] += w2*v.x; accy[c] += w2*v.y;
      }
    }
  }
  float kdx[NCOIL], kdy[NCOIL];
  #pragma unroll
  for (int c = 0; c < NCOIL; ++c){
    kdx[c] = lam*accx[c] + omlam*yre[(size_t)c*NK + k];
    kdy[c] = lam*accy[c] + omlam*yim[(size_t)c*NK + k];
  }
  #pragma unroll
  for (int jx = 0; jx < JW; ++jx){
    int ox = ix[jx]*GRID_N;
    #pragma unroll
    for (int jy = 0; jy < JW; ++jy){
      float w2 = wx[jx]*wy[jy];
      size_t o = (size_t)(ox + iy[jy]);
      #pragma unroll
      for (int c = 0; c < NCOIL; ++c){
        float* dst = HT + ((size_t)c*PLANE + o)*2;
        atomicAdd(dst,   w2*kdx[c]);
        atomicAdd(dst+1, w2*kdy[c]);
      }
    }
  }
}

extern "C" void kernel_launch(void* const* d_in, const int* in_sizes, int n_in,
                              void* d_out, int out_size, void* d_ws, size_t ws_size,
                              hipStream_t stream) {
  const float* ximg  = (const float*)d_in[0];
  const float* yre   = (const float*)d_in[1];
  const float* yim   = (const float*)d_in[2];
  const float* sre   = (const float*)d_in[3];
  const float* sim   = (const float*)d_in[4];
  const float* ktraj = (const float*)d_in[5];
  const float* lraw  = (const float*)d_in[6];
  float* out = (float*)d_out;

  char* ws = (char*)d_ws;
  const size_t REG = 16777216;                 // one planar grid: 512*512*8B*8
  int pairs = (out_size >= 2*IM_N*IM_N) ? 1 : 0;

  // primary layout (50.34 MB):
  //   [0, REG)      A planar; reused after fwd-transpose for kdc/rank/entries
  //   [REG, 2REG)   B planar
  //   [2REG, 3REG)  KTi interleaved; reused as HTi by k_col_accum
  //   [3REG, ...)   sc (1KB), hist (2KB), colOff (2KB)
  const size_t need = 3*REG + 4096 + 2048 + 2048;

  if (ws_size >= need){
    cplx*     A     = (cplx*)ws;
    cplx*     Bb    = (cplx*)(ws + REG);
    float4*   KTi4  = (float4*)(ws + 2*REG);
    float*    sc    = (float*)(ws + 3*REG);
    unsigned* hist  = (unsigned*)(ws + 3*REG + 4096);
    unsigned* colOff= (unsigned*)(ws + 3*REG + 4096 + 2048);
    float4*   kdc4  = (float4*)ws;                       // overlays dead A
    unsigned* rank  = (unsigned*)(ws + (size_t)NK*16*4); // + 8,388,608
    unsigned* entries = (unsigned*)(ws + (size_t)NK*16*4 + (size_t)NK*4);

    const int n4 = NCOIL*PLANE*2/4;

    k_sc_table<<<1,256,0,stream>>>(sc);
    k_zero4<<<(n4+255)/256,256,0,stream>>>((float4*)A, n4);
    k_fill<<<(NCOIL*IM_N*IM_N+255)/256,256,0,stream>>>(ximg, sre, sim, sc, A);

    // fwd fft2/512: rows over x, transpose, rows over y -> Bb = kg^T planar [x][y]
    k_fft_rows<-1><<<NCOIL*GRID_N,256,0,stream>>>(A, 1.0f);
    k_transpose<<<dim3(16,16,NCOIL),dim3(32,8),0,stream>>>(A, Bb);
    k_fft_rows<-1><<<NCOIL*GRID_N,256,0,stream>>>(Bb, 1.0f/(float)GRID_N);

    k_c2i<<<(PLANE*NCOIL+255)/256,256,0,stream>>>((const float2*)Bb, (float2*)KTi4);

    // forward interp + blend -> kdc (A region is dead now)
    k_fwd<<<(NK*4+255)/256,256,0,stream>>>(ktraj, yre, yim, lraw, KTi4, kdc4);

    // column binning (131K int atomics total)
    k_zero1<<<2,256,0,stream>>>((float*)hist, GRID_N);
    k_hist<<<NK/256,256,0,stream>>>(ktraj, hist, rank);
    k_scan512<<<1,GRID_N,0,stream>>>(hist, colOff);
    k_fill_entries<<<NK/256,256,0,stream>>>(ktraj, rank, hist, colOff, entries);

    // adjoint gridding via LDS-atomic column tiles; writes HTi over dead KTi
    k_col_accum<<<GRID_N,256,0,stream>>>(ktraj, entries, colOff, kdc4, KTi4);

    k_i2c<<<(PLANE*NCOIL+255)/256,256,0,stream>>>((const float2*)KTi4, (float2*)Bb);

    // adjoint ifft2*512: rows over y, transpose, rows over x -> A = img [y][x]
    k_fft_rows<+1><<<NCOIL*GRID_N,256,0,stream>>>(Bb, 1.0f);
    k_transpose<<<dim3(16,16,NCOIL),dim3(32,8),0,stream>>>(Bb, A);
    k_fft_rows<+1><<<NCOIL*GRID_N,256,0,stream>>>(A, 1.0f/(float)GRID_N);

    k_zero1<<<(out_size+255)/256,256,0,stream>>>(out, out_size);
    k_final<<<(IM_N*IM_N+255)/256,256,0,stream>>>(A, sre, sim, sc, out, pairs);
  } else {
    // fallback: round-2 validated path (needs 33.6 MB)
    float* sc = (float*)ws;
    cplx*  A  = (cplx*)(ws + 4096);
    cplx*  Bb = (cplx*)(ws + 4096 + REG);
    const int n4 = NCOIL*PLANE*2/4;

    k_sc_table<<<1,256,0,stream>>>(sc);
    k_zero4<<<(n4+255)/256,256,0,stream>>>((float4*)A, n4);
    k_fill<<<(NCOIL*IM_N*IM_N+255)/256,256,0,stream>>>(ximg, sre, sim, sc, A);
    k_fft_rows<-1><<<NCOIL*GRID_N,256,0,stream>>>(A, 1.0f);
    k_transpose<<<dim3(16,16,NCOIL),dim3(32,8),0,stream>>>(A, Bb);
    k_fft_rows<-1><<<NCOIL*GRID_N,256,0,stream>>>(Bb, 1.0f/(float)GRID_N);
    k_zero4<<<(n4+255)/256,256,0,stream>>>((float4*)A, n4);
    k_gather_scatter_fb<<<(NK+255)/256,256,0,stream>>>(ktraj, yre, yim, lraw, Bb, (float*)A);
    k_fft_rows<+1><<<NCOIL*GRID_N,256,0,stream>>>(A, 1.0f);
    k_transpose<<<dim3(16,16,NCOIL),dim3(32,8),0,stream>>>(A, Bb);
    k_fft_rows<+1><<<NCOIL*GRID_N,256,0,stream>>>(Bb, 1.0f/(float)GRID_N);
    k_zero1<<<(out_size+255)/256,256,0,stream>>>(out, out_size);
    k_final<<<(IM_N*IM_N+255)/256,256,0,stream>>>(Bb, sre, sim, sc, out, pairs);
  }
}

// Round 5
// 898.911 us; speedup vs baseline: 3.4014x; 1.0863x over previous
//
#include <hip/hip_runtime.h>
#include <math.h>

#define GRID_N 512
#define IM_N   256
#define NCOIL  8
#define NK     131072
#define PLANE  (GRID_N*GRID_N)
#define JW     6
#define NENT   (NK*JW)
#define BETA_F 13.8551003f   /* pi*sqrt((6/2)^2*(2-0.5)^2 - 0.8) */
#define KSCALE 81.48733086305042f  /* 512/(2*pi) */

struct cplx { float x, y; };

__device__ __forceinline__ float bessel_i0f(float x){
  // Abramowitz & Stegun 9.8.1 / 9.8.2, rel err < 2e-7
  if (x < 3.75f){
    float t = x*(1.0f/3.75f); t = t*t;
    return 1.0f + t*(3.5156229f + t*(3.0899424f + t*(1.2067492f
           + t*(0.2659732f + t*(0.0360768f + t*0.0045813f)))));
  } else {
    float t = 3.75f/x;
    float p = 0.39894228f + t*(0.01328592f + t*(0.00225319f + t*(-0.00157565f
            + t*(0.00916281f + t*(-0.02057706f + t*(0.02635537f
            + t*(-0.01647633f + t*0.00392377f)))))));
    return p * __expf(x) * rsqrtf(x);
  }
}

__device__ __forceinline__ float kb_w(float u){   // 1-axis KB weight, |u|<=3
  float uu = u*(1.0f/3.0f);
  float q = fmaxf(1.0f - uu*uu, 0.0f);
  return bessel_i0f(BETA_F*sqrtf(q)) * (1.0f/6.0f);
}

// Kaiser-Bessel apodization correction row table sc[256]
__global__ void k_sc_table(float* sc){
  int i = threadIdx.x;
  if (i >= IM_N) return;
  float n  = (i - IM_N*0.5f) * (1.0f/GRID_N);
  float pj = 3.14159265358979f * (float)JW * n;
  float t  = BETA_F*BETA_F - pj*pj;
  float sp = sqrtf(fmaxf(t, 1e-12f));
  float sn = sqrtf(fmaxf(-t, 1e-12f));
  float ft = (t > 0.0f) ? (sinhf(sp)/sp) : (sinf(sn)/sn);
  float sc0 = sinhf(BETA_F)/BETA_F;
  sc[i] = sc0/ft;
}

__global__ void k_zero4(float4* p, int n4){
  int i = blockIdx.x*blockDim.x + threadIdx.x;
  if (i < n4) p[i] = make_float4(0.f,0.f,0.f,0.f);
}

__global__ void k_zero1(float* p, int n){
  int i = blockIdx.x*blockDim.x + threadIdx.x;
  if (i < n) p[i] = 0.f;
}

// coil_images * sc2 into padded 512^2 planar grids (A zeroed beforehand)
__global__ void k_fill(const float* __restrict__ ximg, const float* __restrict__ sr,
                       const float* __restrict__ si, const float* __restrict__ sc,
                       cplx* __restrict__ A){
  int idx = blockIdx.x*blockDim.x + threadIdx.x;   // c*65536 + y*256 + x
  if (idx >= NCOIL*IM_N*IM_N) return;
  int c = idx >> 16;
  int pix = idx & 65535;
  int y = pix >> 8, x = pix & 255;
  float v = ximg[pix] * sc[y]*sc[x];
  cplx o; o.x = v * sr[idx]; o.y = v * si[idx];
  A[(size_t)c*PLANE + y*GRID_N + x] = o;
}

// in-place 512-pt radix-2 FFT on each contiguous row; DIR=-1 fwd, +1 inv(unnorm)
template<int DIR>
__global__ void k_fft_rows(cplx* __restrict__ buf, float scale){
  __shared__ cplx lds[GRID_N];
  cplx* p = buf + (size_t)blockIdx.x * GRID_N;
  int tid = threadIdx.x;                       // 256 threads
  for (int i = tid; i < GRID_N; i += 256){
    int r = __brev((unsigned)i) >> 23;         // 9-bit reverse
    lds[r] = p[i];
  }
  __syncthreads();
  for (int half = 1; half < GRID_N; half <<= 1){
    int j = tid & (half-1);
    int k = ((tid & ~(half-1)) << 1) | j;
    float ang = (float)DIR * 3.14159265358979f * (float)j / (float)half;
    float sw, cw; __sincosf(ang, &sw, &cw);
    cplx u = lds[k];
    cplx v = lds[k+half];
    cplx t; t.x = v.x*cw - v.y*sw; t.y = v.x*sw + v.y*cw;
    lds[k].x      = u.x + t.x; lds[k].y      = u.y + t.y;
    lds[k+half].x = u.x - t.x; lds[k+half].y = u.y - t.y;
    __syncthreads();
  }
  for (int i = tid; i < GRID_N; i += 256){
    cplx v = lds[i]; v.x *= scale; v.y *= scale; p[i] = v;
  }
}

// 512x512 tile transpose per coil plane, out[X][Y] = in[Y][X]
__global__ void k_transpose(const cplx* __restrict__ in, cplx* __restrict__ out){
  __shared__ cplx tile[32][33];
  int c  = blockIdx.z;
  int x0 = blockIdx.x*32, y0 = blockIdx.y*32;
  const cplx* ip = in  + (size_t)c*PLANE;
  cplx*       op = out + (size_t)c*PLANE;
  int tx = threadIdx.x, ty = threadIdx.y;      // (32,8)
  for (int dy = 0; dy < 32; dy += 8)
    tile[ty+dy][tx] = ip[(size_t)(y0+ty+dy)*GRID_N + (x0+tx)];
  __syncthreads();
  for (int dy = 0; dy < 32; dy += 8)
    op[(size_t)(x0+ty+dy)*GRID_N + (y0+tx)] = tile[tx][ty+dy];
}

// planar [c][cell] -> coil-interleaved [cell][8 float2]  (fully coalesced)
__global__ void k_c2i(const float2* __restrict__ plan, float2* __restrict__ inter){
  int t = blockIdx.x*blockDim.x + threadIdx.x;
  if (t >= PLANE*NCOIL) return;
  int c = t & 7; int cell = t >> 3;
  inter[(size_t)cell*8 + c] = plan[(size_t)c*PLANE + cell];
}

// coil-interleaved [cell][8 float2] -> planar [c][cell]
__global__ void k_i2c(const float2* __restrict__ inter, float2* __restrict__ plan){
  int t = blockIdx.x*blockDim.x + threadIdx.x;
  if (t >= PLANE*NCOIL) return;
  int c = t & 7; int cell = t >> 3;
  plan[(size_t)c*PLANE + cell] = inter[(size_t)cell*8 + c];
}

// forward interp + lambda blend: thread = (sample, coil-pair).
// p==0 lane also stores the per-sample y-weight table {by, wy0..wy5}.
__global__ __launch_bounds__(256) void k_fwd(
    const float* __restrict__ ktraj, const float* __restrict__ yre,
    const float* __restrict__ yim, const float* __restrict__ lraw,
    const float4* __restrict__ KTi4, float4* __restrict__ kdc4,
    float4* __restrict__ wtab){
  int t = blockIdx.x*blockDim.x + threadIdx.x;
  if (t >= NK*4) return;
  int k = t >> 2, p = t & 3;

  int iy[JW], ix[JW]; float wy[JW], wx[JW];
  float fby;
  {
    float tm = ktraj[k] * KSCALE;
    int base = (int)floorf(tm - 3.0f);
    fby = (float)base;
    #pragma unroll
    for (int j = 1; j <= JW; ++j){
      int fidx = base + j;
      wy[j-1] = kb_w(tm - (float)fidx);
      iy[j-1] = fidx & (GRID_N-1);
    }
  }
  {
    float tm = ktraj[NK + k] * KSCALE;
    int base = (int)floorf(tm - 3.0f);
    #pragma unroll
    for (int j = 1; j <= JW; ++j){
      int fidx = base + j;
      wx[j-1] = kb_w(tm - (float)fidx);
      ix[j-1] = fidx & (GRID_N-1);
    }
  }

  if (p == 0){
    wtab[(size_t)k*2 + 0] = make_float4(fby,   wy[0], wy[1], wy[2]);
    wtab[(size_t)k*2 + 1] = make_float4(wy[3], wy[4], wy[5], 0.f);
  }

  float ax=0.f, ay=0.f, az=0.f, aw=0.f;
  #pragma unroll
  for (int jx = 0; jx < JW; ++jx){
    int ox = ix[jx]*GRID_N;
    #pragma unroll
    for (int jy = 0; jy < JW; ++jy){
      float w2 = wx[jx]*wy[jy];
      float4 v = KTi4[(size_t)(ox + iy[jy])*4 + p];
      ax += w2*v.x; ay += w2*v.y; az += w2*v.z; aw += w2*v.w;
    }
  }
  float lam = 1.0f/(1.0f + __expf(-lraw[0]));
  float oml = 1.0f - lam;
  int c0 = 2*p;
  float4 o;
  o.x = lam*ax + oml*yre[(size_t)c0*NK + k];
  o.y = lam*ay + oml*yim[(size_t)c0*NK + k];
  o.z = lam*az + oml*yre[(size_t)(c0+1)*NK + k];
  o.w = lam*aw + oml*yim[(size_t)(c0+1)*NK + k];
  kdc4[(size_t)k*4 + p] = o;
}

// histogram over x-base bins + per-sample rank
__global__ void k_hist(const float* __restrict__ ktraj, unsigned* __restrict__ hist,
                       unsigned* __restrict__ rank){
  int k = blockIdx.x*blockDim.x + threadIdx.x;
  if (k >= NK) return;
  float tmx = ktraj[NK + k] * KSCALE;
  int bx = (int)floorf(tmx - 3.0f);
  rank[k] = atomicAdd(&hist[bx & (GRID_N-1)], 1u);
}

// column counts + exclusive scan (single block of 512)
__global__ void k_scan512(const unsigned* __restrict__ hist, unsigned* __restrict__ colOff){
  __shared__ unsigned s[GRID_N];
  int t = threadIdx.x;
  unsigned v = 0;
  #pragma unroll
  for (int d = 1; d <= JW; ++d) v += hist[(t - d) & (GRID_N-1)];
  s[t] = v;
  __syncthreads();
  for (int off = 1; off < GRID_N; off <<= 1){
    unsigned add = (t >= off) ? s[t - off] : 0u;
    __syncthreads();
    s[t] += add;
    __syncthreads();
  }
  colOff[t] = (t == 0) ? 0u : s[t-1];
}

// place (column, sample, wx) records at closed-form positions (no contention)
__global__ void k_fill_entries(const float* __restrict__ ktraj,
                               const unsigned* __restrict__ rank,
                               const unsigned* __restrict__ hist,
                               const unsigned* __restrict__ colOff,
                               uint2* __restrict__ entries){
  int k = blockIdx.x*blockDim.x + threadIdx.x;
  if (k >= NK) return;
  float tmx = ktraj[NK + k] * KSCALE;
  int bx = (int)floorf(tmx - 3.0f);
  unsigned r = rank[k];
  unsigned run = 0;
  #pragma unroll
  for (int j = 1; j <= JW; ++j){
    int cc = (bx + j) & (GRID_N-1);
    float wxj = kb_w(tmx - (float)(bx + j));
    entries[colOff[cc] + run + r] = make_uint2((unsigned)k, __float_as_uint(wxj));
    run += hist[cc];
  }
}

// adjoint gridding: block = (x-column, coil-slice); threads parallel over
// entries, accumulate one coil's (re,im) into a 4KB LDS tile via ds_add_f32.
__global__ __launch_bounds__(256) void k_col_accum2(
    const uint2* __restrict__ entries, const unsigned* __restrict__ colOff,
    const float4* __restrict__ wtab,    // [k]: {by,wy0,wy1,wy2},{wy3,wy4,wy5,-}
    const float2* __restrict__ kdc2,    // [k][8] float2 (per-coil re,im)
    float2* __restrict__ HT2){          // [cell][8] float2
  __shared__ float acc[2*GRID_N];
  const int c = blockIdx.x, s = blockIdx.y;
  const int tid = threadIdx.x;
  for (int i = tid; i < 2*GRID_N; i += 256) acc[i] = 0.f;
  __syncthreads();

  unsigned beg = colOff[c];
  unsigned end = (c < GRID_N-1) ? colOff[c+1] : (unsigned)NENT;

  for (unsigned e = beg + tid; e < end; e += 256){
    uint2 en = entries[e];
    unsigned kk = en.x;
    float wx = __uint_as_float(en.y);
    float4 w0 = wtab[(size_t)kk*2 + 0];
    float4 w1 = wtab[(size_t)kk*2 + 1];
    float2 v  = kdc2[(size_t)kk*8 + s];
    int by = (int)w0.x;
    float vr = v.x, vi = v.y;
    int y; float w;
    y = (by+1)&(GRID_N-1); w = wx*w0.y; atomicAdd(&acc[y], w*vr); atomicAdd(&acc[GRID_N+y], w*vi);
    y = (by+2)&(GRID_N-1); w = wx*w0.z; atomicAdd(&acc[y], w*vr); atomicAdd(&acc[GRID_N+y], w*vi);
    y = (by+3)&(GRID_N-1); w = wx*w0.w; atomicAdd(&acc[y], w*vr); atomicAdd(&acc[GRID_N+y], w*vi);
    y = (by+4)&(GRID_N-1); w = wx*w1.x; atomicAdd(&acc[y], w*vr); atomicAdd(&acc[GRID_N+y], w*vi);
    y = (by+5)&(GRID_N-1); w = wx*w1.y; atomicAdd(&acc[y], w*vr); atomicAdd(&acc[GRID_N+y], w*vi);
    y = (by+6)&(GRID_N-1); w = wx*w1.z; atomicAdd(&acc[y], w*vr); atomicAdd(&acc[GRID_N+y], w*vi);
  }
  __syncthreads();

  for (int y = tid; y < GRID_N; y += 256)
    HT2[((size_t)c*GRID_N + y)*8 + s] = make_float2(acc[y], acc[GRID_N+y]);
}

// crop, apodize, conj(smaps) coil-combine; ACCUMULATES into out
__global__ void k_final(const cplx* __restrict__ Bg, const float* __restrict__ sr,
                        const float* __restrict__ si, const float* __restrict__ sc,
                        float* __restrict__ out, int pairs){
  int idx = blockIdx.x*blockDim.x + threadIdx.x;   // y*256+x
  if (idx >= IM_N*IM_N) return;
  int y = idx >> 8, x = idx & 255;
  float s2 = sc[y]*sc[x];
  float ax = 0.f, ay = 0.f;
  #pragma unroll
  for (int c = 0; c < NCOIL; ++c){
    cplx v = Bg[(size_t)c*PLANE + y*GRID_N + x];
    int gi = (c << 16) | idx;
    float rr = sr[gi], ii = si[gi];
    ax += rr*v.x + ii*v.y;      // conj(s)*v real
    ay += rr*v.y - ii*v.x;      // conj(s)*v imag
  }
  if (pairs){
    out[idx*2]   += ax * s2;
    out[idx*2+1] += ay * s2;
  } else {
    out[idx]     += ax * s2;
  }
}

// ---------------- fallback (round-2 validated fused atomic path) -------------
__global__ void k_gather_scatter_fb(const float* __restrict__ ktraj,
                                    const float* __restrict__ yre,
                                    const float* __restrict__ yim,
                                    const float* __restrict__ lraw,
                                    const cplx* __restrict__ KT,
                                    float* __restrict__ HT){
  int k = blockIdx.x*blockDim.x + threadIdx.x;
  if (k >= NK) return;
  float lam   = 1.0f/(1.0f + __expf(-lraw[0]));
  float omlam = 1.0f - lam;
  int iy[JW], ix[JW]; float wy[JW], wx[JW];
  {
    float tm = ktraj[k] * KSCALE;
    int base = (int)floorf(tm - 3.0f);
    #pragma unroll
    for (int j = 1; j <= JW; ++j){
      wy[j-1] = kb_w(tm - (float)(base+j));
      iy[j-1] = (base+j) & (GRID_N-1);
    }
  }
  {
    float tm = ktraj[NK + k] * KSCALE;
    int base = (int)floorf(tm - 3.0f);
    #pragma unroll
    for (int j = 1; j <= JW; ++j){
      wx[j-1] = kb_w(tm - (float)(base+j));
      ix[j-1] = (base+j) & (GRID_N-1);
    }
  }
  float accx[NCOIL], accy[NCOIL];
  #pragma unroll
  for (int c = 0; c < NCOIL; ++c){ accx[c]=0.f; accy[c]=0.f; }
  #pragma unroll
  for (int jx = 0; jx < JW; ++jx){
    int ox = ix[jx]*GRID_N;
    #pragma unroll
    for (int jy = 0; jy < JW; ++jy){
      float w2 = wx[jx]*wy[jy];
      size_t o = (size_t)(ox + iy[jy]);
      #pragma unroll
      for (int c = 0; c < NCOIL; ++c){
        cplx v = KT[(size_t)c*PLANE + o];
        accx[c] += w2*v.x; accy[c] += w2*v.y;
      }
    }
  }
  float kdx[NCOIL], kdy[NCOIL];
  #pragma unroll
  for (int c = 0; c < NCOIL; ++c){
    kdx[c] = lam*accx[c] + omlam*yre[(size_t)c*NK + k];
    kdy[c] = lam*accy[c] + omlam*yim[(size_t)c*NK + k];
  }
  #pragma unroll
  for (int jx = 0; jx < JW; ++jx){
    int ox = ix[jx]*GRID_N;
    #pragma unroll
    for (int jy = 0; jy < JW; ++jy){
      float w2 = wx[jx]*wy[jy];
      size_t o = (size_t)(ox + iy[jy]);
      #pragma unroll
      for (int c = 0; c < NCOIL; ++c){
        float* dst = HT + ((size_t)c*PLANE + o)*2;
        atomicAdd(dst,   w2*kdx[c]);
        atomicAdd(dst+1, w2*kdy[c]);
      }
    }
  }
}

extern "C" void kernel_launch(void* const* d_in, const int* in_sizes, int n_in,
                              void* d_out, int out_size, void* d_ws, size_t ws_size,
                              hipStream_t stream) {
  const float* ximg  = (const float*)d_in[0];
  const float* yre   = (const float*)d_in[1];
  const float* yim   = (const float*)d_in[2];
  const float* sre   = (const float*)d_in[3];
  const float* sim   = (const float*)d_in[4];
  const float* ktraj = (const float*)d_in[5];
  const float* lraw  = (const float*)d_in[6];
  float* out = (float*)d_out;

  char* ws = (char*)d_ws;
  const size_t REG = 16777216;                 // one planar grid: 512*512*8B*8
  int pairs = (out_size >= 2*IM_N*IM_N) ? 1 : 0;

  // primary layout (50.34 MB):
  //   [0, REG)      A planar; later kdc (8MB) + rank (0.5MB) + entries (6.3MB)
  //   [REG, 2REG)   B planar; later wtab (4MB); later planar H / img
  //   [2REG, 3REG)  KTi interleaved; reused as HTi by k_col_accum2
  //   [3REG, ...)   sc (4KB), hist (2KB), colOff (2KB)
  const size_t need = 3*REG + 4096 + 2048 + 2048;

  if (ws_size >= need){
    cplx*     A     = (cplx*)ws;
    cplx*     Bb    = (cplx*)(ws + REG);
    float4*   KTi4  = (float4*)(ws + 2*REG);
    float*    sc    = (float*)(ws + 3*REG);
    unsigned* hist  = (unsigned*)(ws + 3*REG + 4096);
    unsigned* colOff= (unsigned*)(ws + 3*REG + 4096 + 2048);
    float4*   kdc4  = (float4*)ws;                         // overlays dead A
    unsigned* rank  = (unsigned*)(ws + (size_t)NK*16*4);   // +8,388,608
    uint2*    entries = (uint2*)(ws + (size_t)NK*16*4 + (size_t)NK*4);
    float4*   wtab  = (float4*)(ws + REG);                 // overlays dead Bb

    const int n4 = NCOIL*PLANE*2/4;

    k_sc_table<<<1,256,0,stream>>>(sc);
    k_zero4<<<(n4+255)/256,256,0,stream>>>((float4*)A, n4);
    k_fill<<<(NCOIL*IM_N*IM_N+255)/256,256,0,stream>>>(ximg, sre, sim, sc, A);

    // fwd fft2/512: rows over x, transpose, rows over y -> Bb = kg^T planar [x][y]
    k_fft_rows<-1><<<NCOIL*GRID_N,256,0,stream>>>(A, 1.0f);
    k_transpose<<<dim3(16,16,NCOIL),dim3(32,8),0,stream>>>(A, Bb);
    k_fft_rows<-1><<<NCOIL*GRID_N,256,0,stream>>>(Bb, 1.0f/(float)GRID_N);

    k_c2i<<<(PLANE*NCOIL+255)/256,256,0,stream>>>((const float2*)Bb, (float2*)KTi4);

    // forward interp + blend -> kdc; also emits wtab (Bb planar is dead)
    k_fwd<<<(NK*4+255)/256,256,0,stream>>>(ktraj, yre, yim, lraw, KTi4, kdc4, wtab);

    // column binning (131K int atomics total)
    k_zero1<<<2,256,0,stream>>>((float*)hist, GRID_N);
    k_hist<<<NK/256,256,0,stream>>>(ktraj, hist, rank);
    k_scan512<<<1,GRID_N,0,stream>>>(hist, colOff);
    k_fill_entries<<<NK/256,256,0,stream>>>(ktraj, rank, hist, colOff, entries);

    // adjoint gridding: 512 columns x 8 coil-slices, 4KB LDS tiles, no merge
    k_col_accum2<<<dim3(GRID_N,NCOIL),256,0,stream>>>(entries, colOff, wtab,
                                                      (const float2*)kdc4,
                                                      (float2*)KTi4);

    k_i2c<<<(PLANE*NCOIL+255)/256,256,0,stream>>>((const float2*)KTi4, (float2*)Bb);

    // adjoint ifft2*512: rows over y, transpose, rows over x -> A = img [y][x]
    k_fft_rows<+1><<<NCOIL*GRID_N,256,0,stream>>>(Bb, 1.0f);
    k_transpose<<<dim3(16,16,NCOIL),dim3(32,8),0,stream>>>(Bb, A);
    k_fft_rows<+1><<<NCOIL*GRID_N,256,0,stream>>>(A, 1.0f/(float)GRID_N);

    k_zero1<<<(out_size+255)/256,256,0,stream>>>(out, out_size);
    k_final<<<(IM_N*IM_N+255)/256,256,0,stream>>>(A, sre, sim, sc, out, pairs);
  } else {
    // fallback: round-2 validated path (needs 33.6 MB)
    float* sc = (float*)ws;
    cplx*  A  = (cplx*)(ws + 4096);
    cplx*  Bb = (cplx*)(ws + 4096 + REG);
    const int n4 = NCOIL*PLANE*2/4;

    k_sc_table<<<1,256,0,stream>>>(sc);
    k_zero4<<<(n4+255)/256,256,0,stream>>>((float4*)A, n4);
    k_fill<<<(NCOIL*IM_N*IM_N+255)/256,256,0,stream>>>(ximg, sre, sim, sc, A);
    k_fft_rows<-1><<<NCOIL*GRID_N,256,0,stream>>>(A, 1.0f);
    k_transpose<<<dim3(16,16,NCOIL),dim3(32,8),0,stream>>>(A, Bb);
    k_fft_rows<-1><<<NCOIL*GRID_N,256,0,stream>>>(Bb, 1.0f/(float)GRID_N);
    k_zero4<<<(n4+255)/256,256,0,stream>>>((float4*)A, n4);
    k_gather_scatter_fb<<<(NK+255)/256,256,0,stream>>>(ktraj, yre, yim, lraw, Bb, (float*)A);
    k_fft_rows<+1><<<NCOIL*GRID_N,256,0,stream>>>(A, 1.0f);
    k_transpose<<<dim3(16,16,NCOIL),dim3(32,8),0,stream>>>(A, Bb);
    k_fft_rows<+1><<<NCOIL*GRID_N,256,0,stream>>>(Bb, 1.0f/(float)GRID_N);
    k_zero1<<<(out_size+255)/256,256,0,stream>>>(out, out_size);
    k_final<<<(IM_N*IM_N+255)/256,256,0,stream>>>(Bb, sre, sim, sc, out, pairs);
  }
}